// Round 2
// baseline (648.676 us; speedup 1.0000x reference)
//
#include <hip/hip_runtime.h>
#include <math.h>

#define B_   8
#define C_   64
#define N_   4096
#define PAD  68   // floats per LDS row: 16B-aligned float4 rows, checked bank patterns
#define NT   64   // key tiles of 64

// One WG per (batch, 64-query block). 256 threads = 4 waves.
// Wave w owns query rows [w*16, w*16+16); lane: t0 = w*16 + (lane>>4)*4 (4 rows),
// f0 = (lane&15)*4 (4 S-cols / PT-rows), cl = lane&15 (PV ci base, ci = cl+16*cs).
__global__ __launch_bounds__(256) void fused_attn_f32(
    const float* __restrict__ x, const float* __restrict__ y,
    const float* __restrict__ Wq, const float* __restrict__ bq,
    const float* __restrict__ Wk, const float* __restrict__ bk,
    const float* __restrict__ Wv, const float* __restrict__ bv,
    const float* __restrict__ gammap, float* __restrict__ out)
{
    __shared__ __align__(16) float bufY[C_*PAD];   // Wk (ph2) | y tile | PYn (epilogue)
    __shared__ __align__(16) float bufB[C_*PAD];   // qchan (ph1/2) | P^T tile | Wv (epilogue)
    __shared__ __align__(16) float qwT[C_*PAD];    // qw^T[ci][t]
    __shared__ __align__(16) float qbs[C_];        // qb[t] = Qb row t . bk
    __shared__ float wqr[C_];

    const int tid  = threadIdx.x;
    const int lane = tid & 63;
    const int w    = tid >> 6;
    const int b    = blockIdx.x >> 6;
    const int blk  = blockIdx.x & 63;

    const float* __restrict__ xb = x + (size_t)b * (C_*N_);
    const float* __restrict__ yb = y + (size_t)b * (C_*N_);

    if (tid < C_) wqr[tid] = Wq[blk*C_ + tid];
    __syncthreads();

    // ---- Phase 1: qchan_blk (= Q-block 64x64 via the reshape reinterpretation)
    // qchan[p] = bq[blk] + sum_cx Wq[blk,cx] * x[b,cx,p];  Qb[t][c] = qchan[64t+c]
    {
        const float bqv = bq[blk];
        #pragma unroll
        for (int u = 0; u < 4; ++u) {
            const int p = u*1024 + tid*4;
            float a0=bqv, a1=bqv, a2=bqv, a3=bqv;
            #pragma unroll 8
            for (int cx = 0; cx < C_; ++cx) {
                const float wv = wqr[cx];
                const float4 xv = *(const float4*)(xb + cx*N_ + p);
                a0 = fmaf(wv, xv.x, a0);
                a1 = fmaf(wv, xv.y, a1);
                a2 = fmaf(wv, xv.z, a2);
                a3 = fmaf(wv, xv.w, a3);
            }
            const int t = p >> 6, c = p & 63;
            *(float4*)(&bufB[t*PAD + c]) = make_float4(a0,a1,a2,a3);
        }
        // stage Wk flat into bufY (independent of phase 1)
        #pragma unroll
        for (int u = 0; u < 4; ++u) {
            const int idx = u*1024 + tid*4;
            *(float4*)(&bufY[idx]) = *(const float4*)(Wk + idx);
        }
    }
    __syncthreads();

    // ---- Phase 2: qw^T[ci][t] = sum_c Qb[t][c]*Wk[c][ci];  qb[t] = Qb[t].bk
    {
        const int t   = lane;
        const int ci0 = w*16;
        float acc[16];
        #pragma unroll
        for (int r = 0; r < 16; ++r) acc[r] = 0.f;
        #pragma unroll 4
        for (int c = 0; c < C_; ++c) {
            const float qv = bufB[t*PAD + c];
            #pragma unroll
            for (int uu = 0; uu < 4; ++uu) {
                const float4 wk4 = *(const float4*)(&bufY[c*C_ + ci0 + uu*4]);
                acc[uu*4+0] = fmaf(qv, wk4.x, acc[uu*4+0]);
                acc[uu*4+1] = fmaf(qv, wk4.y, acc[uu*4+1]);
                acc[uu*4+2] = fmaf(qv, wk4.z, acc[uu*4+2]);
                acc[uu*4+3] = fmaf(qv, wk4.w, acc[uu*4+3]);
            }
        }
        #pragma unroll
        for (int r = 0; r < 16; ++r) qwT[(ci0 + r)*PAD + t] = acc[r];
        if (w == 0) {
            float qa = 0.f;
            #pragma unroll 8
            for (int c = 0; c < C_; ++c) qa += bufB[t*PAD + c] * bk[c];
            qbs[t] = qa;
        }
    }
    __syncthreads();

    // ---- Main loop over 64 key tiles (flash-style online softmax)
    const int tq = lane >> 4;
    const int t0 = w*16 + tq*4;
    const int f0 = (lane & 15) * 4;
    const int cl = lane & 15;

    float m[4], l[4], PY[4][4];
    #pragma unroll
    for (int i = 0; i < 4; ++i) {
        m[i] = -INFINITY; l[i] = 0.f;
        #pragma unroll
        for (int cs = 0; cs < 4; ++cs) PY[i][cs] = 0.f;
    }
    const float4 qbv = *(const float4*)(&qbs[t0]);
    const float qba[4] = {qbv.x, qbv.y, qbv.z, qbv.w};

    for (int jt = 0; jt < NT; ++jt) {
        __syncthreads();
        // stage y tile [64 ci][64 j] into bufY (coalesced float4)
        #pragma unroll
        for (int u = 0; u < 4; ++u) {
            const int f = u*256 + tid;
            const int ci = f >> 4, j4 = (f & 15)*4;
            *(float4*)(&bufY[ci*PAD + j4]) =
                *(const float4*)(yb + ci*N_ + jt*64 + j4);
        }
        __syncthreads();

        // S[t0+i][f0+j] = qb + sum_ci qw[t][ci]*y[ci][j]
        float S[4][4];
        #pragma unroll
        for (int i=0;i<4;++i)
            #pragma unroll
            for (int j=0;j<4;++j) S[i][j] = qba[i];

        #pragma unroll 4
        for (int ci = 0; ci < C_; ++ci) {
            const float4 qv = *(const float4*)(&qwT[ci*PAD + t0]);
            const float4 yv = *(const float4*)(&bufY[ci*PAD + f0]);
            const float qa[4] = {qv.x,qv.y,qv.z,qv.w};
            const float ya[4] = {yv.x,yv.y,yv.z,yv.w};
            #pragma unroll
            for (int i=0;i<4;++i)
                #pragma unroll
                for (int j=0;j<4;++j)
                    S[i][j] = fmaf(qa[i], ya[j], S[i][j]);
        }

        // online softmax update; row spread over 16 lanes (bits 0..3 of lane)
        #pragma unroll
        for (int i=0;i<4;++i) {
            float rm = fmaxf(fmaxf(S[i][0],S[i][1]), fmaxf(S[i][2],S[i][3]));
            rm = fmaxf(rm, __shfl_xor(rm, 1));
            rm = fmaxf(rm, __shfl_xor(rm, 2));
            rm = fmaxf(rm, __shfl_xor(rm, 4));
            rm = fmaxf(rm, __shfl_xor(rm, 8));
            const float mn = fmaxf(m[i], rm);
            const float sc = __expf(m[i] - mn);   // exp(-inf)=0 on first tile
            m[i] = mn;
            float rs = 0.f;
            #pragma unroll
            for (int j=0;j<4;++j) { S[i][j] = __expf(S[i][j] - mn); rs += S[i][j]; }
            rs += __shfl_xor(rs, 1);
            rs += __shfl_xor(rs, 2);
            rs += __shfl_xor(rs, 4);
            rs += __shfl_xor(rs, 8);
            l[i] = l[i]*sc + rs;
            #pragma unroll
            for (int cs=0;cs<4;++cs) PY[i][cs] *= sc;
        }

        // write P^T[j][t] tile (wave-local rows, barrier for safety this round)
        #pragma unroll
        for (int j=0;j<4;++j) {
            *(float4*)(&bufB[(f0+j)*PAD + t0]) =
                make_float4(S[0][j],S[1][j],S[2][j],S[3][j]);
        }
        __syncthreads();

        // PY[t][ci] += sum_j P[t][j]*y[ci][j];  lane: ci = cl + 16*cs
        #pragma unroll 4
        for (int j = 0; j < C_; ++j) {
            const float4 pv = *(const float4*)(&bufB[j*PAD + t0]);
            const float pa[4] = {pv.x,pv.y,pv.z,pv.w};
            float ya[4];
            #pragma unroll
            for (int cs=0;cs<4;++cs) ya[cs] = bufY[(cl + 16*cs)*PAD + j];
            #pragma unroll
            for (int i=0;i<4;++i)
                #pragma unroll
                for (int cs=0;cs<4;++cs)
                    PY[i][cs] = fmaf(pa[i], ya[cs], PY[i][cs]);
        }
    }

    __syncthreads();
    // normalized PY -> bufY; Wv flat -> bufB
    #pragma unroll
    for (int i=0;i<4;++i) {
        const float rinv = 1.0f / l[i];
        #pragma unroll
        for (int cs=0;cs<4;++cs)
            bufY[(t0+i)*PAD + cl + 16*cs] = PY[i][cs] * rinv;
    }
    #pragma unroll
    for (int u = 0; u < 4; ++u) {
        const int idx = u*1024 + tid*4;
        *(float4*)(&bufB[idx]) = *(const float4*)(Wv + idx);
    }
    __syncthreads();

    // epilogue: out[b, c, blk*64 + t] = gamma*(sum_ci Wv[c][ci]*PYn[t][ci] + bv[c]) + x
    const float g0 = gammap[0];
    float accs[16];
    #pragma unroll
    for (int s2=0;s2<16;++s2) accs[s2]=0.f;
    #pragma unroll 2
    for (int ci = 0; ci < C_; ++ci) {
        const float pvv = bufY[lane*PAD + ci];
        #pragma unroll
        for (int s2=0;s2<16;++s2)
            accs[s2] = fmaf(pvv, bufB[(w*16+s2)*C_ + ci], accs[s2]);
    }
    const size_t obase = (size_t)b*(size_t)(C_*N_) + (size_t)(blk*64 + lane);
    #pragma unroll
    for (int s2=0;s2<16;++s2) {
        const int c = w*16 + s2;
        out[obase + (size_t)c*N_] = g0*(accs[s2] + bv[c]) + x[obase + (size_t)c*N_];
    }
}

extern "C" void kernel_launch(void* const* d_in, const int* in_sizes, int n_in,
                              void* d_out, int out_size, void* d_ws, size_t ws_size,
                              hipStream_t stream) {
    const float* x  = (const float*)d_in[0];
    const float* y  = (const float*)d_in[1];
    const float* Wq = (const float*)d_in[2];
    const float* bq = (const float*)d_in[3];
    const float* Wk = (const float*)d_in[4];
    const float* bk = (const float*)d_in[5];
    const float* Wv = (const float*)d_in[6];
    const float* bv = (const float*)d_in[7];
    const float* g  = (const float*)d_in[8];
    float* outp = (float*)d_out;
    dim3 grid(B_ * 64), block(256);
    hipLaunchKernelGGL(fused_attn_f32, grid, block, 0, stream,
                       x, y, Wq, bq, Wk, bk, Wv, bv, g, outp);
}

// Round 3
// 224.287 us; speedup vs baseline: 2.8922x; 2.8922x over previous
//
#include <hip/hip_runtime.h>
#include <math.h>

#define Bb 8
#define Cc 64
#define Nn 4096

typedef __attribute__((ext_vector_type(8))) short bf16x8;
typedef __attribute__((ext_vector_type(4))) float f32x4;
typedef __attribute__((ext_vector_type(4))) int   i32x4;

#define MFMA(a,b,c) __builtin_amdgcn_mfma_f32_16x16x32_bf16((a),(b),(c),0,0,0)

__device__ __forceinline__ unsigned short f2bf(float f){
    unsigned uu = __float_as_uint(f);
    return (unsigned short)((uu + 0x7FFFu + ((uu>>16)&1u)) >> 16);
}
// byte address of a 16B slot inside a 128B row, XOR-swizzled for bank balance
__device__ __forceinline__ int swzaddr(int row, int slot){
    int h = (row ^ (row>>3)) & 7;
    return row*128 + (((slot ^ h)&7)<<4);
}

// Region B offsets (bytes): yt [64ci][64j] bf16 @0 (8KB), ytT [64j][64ci] bf16 @8192 (8KB),
// P/PYn [128t][64] bf16 @16384 (16KB). Phase2 aliases Wk f32 (16KB) @0.
#define YT0   0
#define YTT0  8192
#define P0    16384

__global__ __launch_bounds__(512, 2) void fused_attn_mfma(
    const float* __restrict__ x, const float* __restrict__ y,
    const float* __restrict__ Wq, const float* __restrict__ bq,
    const float* __restrict__ Wk, const float* __restrict__ bk,
    const float* __restrict__ Wv, const float* __restrict__ bv,
    const float* __restrict__ gammap, float* __restrict__ out)
{
    __shared__ __align__(16) float QbL[2*4096];          // 32KB: phase1/2 Qb; later qwbf (bf16, 16KB)
    __shared__ __align__(16) unsigned char RBp[32768];   // region B
    __shared__ float qbsL[128];
    __shared__ float WqL[128];
    __shared__ float bqL[2];
    __shared__ float bkL[64];

    const int tid = threadIdx.x;
    const int l   = tid & 63;
    const int w   = tid >> 6;          // wave 0..7
    const int l15 = l & 15;
    const int u   = l >> 4;            // 0..3
    const int b   = blockIdx.x >> 5;
    const int pb  = blockIdx.x & 31;   // pair of q-blocks
    const int c0  = pb*2;              // q channels c0, c0+1
    const int p0  = pb*128;            // output spatial base

    const float* __restrict__ xb = x + (size_t)b*Cc*Nn;
    const float* __restrict__ yb = y + (size_t)b*Cc*Nn;

    // ---- stage params
    if (tid < 128) WqL[tid] = Wq[c0*64 + tid];
    if (tid < 2)   bqL[tid] = bq[c0 + tid];
    if (tid < 64)  bkL[tid] = bk[tid];
    {
        float* WkL = (float*)RBp;
        #pragma unroll
        for (int q2 = 0; q2 < 2; ++q2){
            const int idx = tid*8 + q2*4;
            *(float4*)(&WkL[idx]) = *(const float4*)(Wk + idx);
        }
    }
    __syncthreads();

    // ---- phase 1: qchan for channels c0, c0+1 (full spatial) -> QbL
    {
        const int pp = tid*8;
        float q0[8], q1[8];
        const float bq0 = bqL[0], bq1 = bqL[1];
        #pragma unroll
        for (int k2=0;k2<8;++k2){ q0[k2]=bq0; q1[k2]=bq1; }
        #pragma unroll 4
        for (int cx=0; cx<64; ++cx){
            const float wa = WqL[cx], wb = WqL[64+cx];
            const float4 x0 = *(const float4*)(xb + cx*Nn + pp);
            const float4 x1 = *(const float4*)(xb + cx*Nn + pp + 4);
            q0[0]=fmaf(wa,x0.x,q0[0]); q0[1]=fmaf(wa,x0.y,q0[1]);
            q0[2]=fmaf(wa,x0.z,q0[2]); q0[3]=fmaf(wa,x0.w,q0[3]);
            q0[4]=fmaf(wa,x1.x,q0[4]); q0[5]=fmaf(wa,x1.y,q0[5]);
            q0[6]=fmaf(wa,x1.z,q0[6]); q0[7]=fmaf(wa,x1.w,q0[7]);
            q1[0]=fmaf(wb,x0.x,q1[0]); q1[1]=fmaf(wb,x0.y,q1[1]);
            q1[2]=fmaf(wb,x0.z,q1[2]); q1[3]=fmaf(wb,x0.w,q1[3]);
            q1[4]=fmaf(wb,x1.x,q1[4]); q1[5]=fmaf(wb,x1.y,q1[5]);
            q1[6]=fmaf(wb,x1.z,q1[6]); q1[7]=fmaf(wb,x1.w,q1[7]);
        }
        *(float4*)(&QbL[pp])        = make_float4(q0[0],q0[1],q0[2],q0[3]);
        *(float4*)(&QbL[pp+4])      = make_float4(q0[4],q0[5],q0[6],q0[7]);
        *(float4*)(&QbL[4096+pp])   = make_float4(q1[0],q1[1],q1[2],q1[3]);
        *(float4*)(&QbL[4096+pp+4]) = make_float4(q1[4],q1[5],q1[6],q1[7]);
    }
    __syncthreads();

    // ---- phase 2: qb[t] (VALU, 128 thr) and qw^T = Wk^T(ci,c) @ Qb^T(c,t) via MFMA
    if (tid < 128) {
        const float* qr = &QbL[(tid>>6)*4096 + (tid&63)*64];
        float a = 0.f;
        #pragma unroll 8
        for (int c=0;c<64;++c) a = fmaf(qr[c], bkL[c], a);
        qbsL[tid] = a;
    }
    f32x4 D2[4];
    {
        const float* WkL = (const float*)RBp;
        bf16x8 wkA[4][2];
        #pragma unroll
        for (int mb=0; mb<4; ++mb){
            const int ci = mb*16 + l15;
            #pragma unroll
            for (int kc=0; kc<2; ++kc){
                bf16x8 t;
                #pragma unroll
                for (int i=0;i<8;++i) t[i] = (short)f2bf(WkL[(kc*32 + u*8 + i)*64 + ci]);
                wkA[mb][kc] = t;
            }
        }
        bf16x8 qbB[2];
        {
            const int t = w*16 + l15;
            const float* qr = &QbL[(t>>6)*4096 + (t&63)*64];
            #pragma unroll
            for (int kc=0; kc<2; ++kc){
                const float4 f0 = *(const float4*)(qr + kc*32 + u*8);
                const float4 f1 = *(const float4*)(qr + kc*32 + u*8 + 4);
                bf16x8 t;
                t[0]=(short)f2bf(f0.x); t[1]=(short)f2bf(f0.y);
                t[2]=(short)f2bf(f0.z); t[3]=(short)f2bf(f0.w);
                t[4]=(short)f2bf(f1.x); t[5]=(short)f2bf(f1.y);
                t[6]=(short)f2bf(f1.z); t[7]=(short)f2bf(f1.w);
                qbB[kc] = t;
            }
        }
        #pragma unroll
        for (int mb=0;mb<4;++mb){
            f32x4 d = {0.f,0.f,0.f,0.f};
            d = MFMA(wkA[mb][0], qbB[0], d);
            d = MFMA(wkA[mb][1], qbB[1], d);
            D2[mb] = d;
        }
    }
    __syncthreads();   // Qb reads done everywhere; qbsL ready

    // write qw (bf16, swizzled [t][ci]) into QbL region; reads are wave-local
    unsigned char* QWp = (unsigned char*)QbL;
    {
        const int t = w*16 + l15;
        #pragma unroll
        for (int mb=0;mb<4;++mb){
            #pragma unroll
            for (int r=0;r<4;++r){
                const int ci = mb*16 + u*4 + r;
                *(unsigned short*)(QWp + swzaddr(t, ci>>3) + (ci&7)*2) = f2bf(D2[mb][r]);
            }
        }
    }
    bf16x8 qwA0, qwA1;
    {
        const int t = w*16 + l15;
        qwA0 = *(const bf16x8*)(QWp + swzaddr(t, u));
        qwA1 = *(const bf16x8*)(QWp + swzaddr(t, 4 + u));
    }
    float qb4[4];
    #pragma unroll
    for (int r=0;r<4;++r) qb4[r] = qbsL[w*16 + u*4 + r];

    // ---- precompute main-loop LDS addresses (loop-invariant)
    const int sci = tid >> 3;           // staging: ci row 0..63
    const int sjj = (tid & 7) * 8;      // staging: j base
    int rA[4][2], paA[2], pwA2[4][4], trA[8];
    #pragma unroll
    for (int nb=0;nb<4;++nb){
        const int row = 16*nb + l15;
        rA[nb][0] = swzaddr(row, u);
        rA[nb][1] = swzaddr(row, 4 + u);
    }
    paA[0] = P0 + swzaddr(w*16 + l15, u);
    paA[1] = P0 + swzaddr(w*16 + l15, 4 + u);
    #pragma unroll
    for (int r=0;r<4;++r){
        const int trow = w*16 + u*4 + r;
        #pragma unroll
        for (int nb=0;nb<4;++nb)
            pwA2[r][nb] = P0 + swzaddr(trow, (l15>>3) + 2*nb) + (l&7)*2;
    }
    const int natA = YT0 + swzaddr(sci, tid & 7);
    #pragma unroll
    for (int k=0;k<8;++k)
        trA[k] = YTT0 + swzaddr(sjj + k, sci>>3) + (sci&7)*2;

    // ---- flash state
    f32x4 PY[4];
    #pragma unroll
    for (int nb=0;nb<4;++nb) PY[nb] = (f32x4){0.f,0.f,0.f,0.f};
    float m4[4], l4[4];
    #pragma unroll
    for (int r=0;r<4;++r){ m4[r] = -1.0e30f; l4[r] = 0.f; }

    const float* ybt = yb + sci*Nn + sjj;
    float4 ra0 = *(const float4*)(ybt);
    float4 ra1 = *(const float4*)(ybt + 4);
    float4 rb0, rb1;

    auto tile_body = [&](int jt, float4& A0, float4& A1, float4& N0, float4& N1) {
        // stage tile jt (from regs) into LDS, both layouts, bf16
        unsigned short e0=f2bf(A0.x), e1=f2bf(A0.y), e2=f2bf(A0.z), e3=f2bf(A0.w);
        unsigned short e4=f2bf(A1.x), e5=f2bf(A1.y), e6=f2bf(A1.z), e7=f2bf(A1.w);
        i32x4 pk;
        pk.x = (int)e0 | ((int)e1<<16);
        pk.y = (int)e2 | ((int)e3<<16);
        pk.z = (int)e4 | ((int)e5<<16);
        pk.w = (int)e6 | ((int)e7<<16);
        *(i32x4*)(RBp + natA) = pk;
        *(unsigned short*)(RBp + trA[0]) = e0;
        *(unsigned short*)(RBp + trA[1]) = e1;
        *(unsigned short*)(RBp + trA[2]) = e2;
        *(unsigned short*)(RBp + trA[3]) = e3;
        *(unsigned short*)(RBp + trA[4]) = e4;
        *(unsigned short*)(RBp + trA[5]) = e5;
        *(unsigned short*)(RBp + trA[6]) = e6;
        *(unsigned short*)(RBp + trA[7]) = e7;
        __syncthreads();
        // prefetch next tile (overlaps compute)
        {
            const float* yn = ybt + ((jt+1)&63)*64;
            N0 = *(const float4*)(yn);
            N1 = *(const float4*)(yn + 4);
        }
        // S = qw @ y_tile  (+qb via C-init)
        f32x4 S[4];
        #pragma unroll
        for (int nb=0;nb<4;++nb){
            f32x4 s = (f32x4){qb4[0],qb4[1],qb4[2],qb4[3]};
            s = MFMA(qwA0, *(const bf16x8*)(RBp + YTT0 + rA[nb][0]), s);
            s = MFMA(qwA1, *(const bf16x8*)(RBp + YTT0 + rA[nb][1]), s);
            S[nb] = s;
        }
        // online softmax (rows spread over 16 lanes; 4 rows/lane)
        float pm[4];
        #pragma unroll
        for (int r=0;r<4;++r)
            pm[r] = fmaxf(fmaxf(S[0][r],S[1][r]), fmaxf(S[2][r],S[3][r]));
        #pragma unroll
        for (int st=1; st<16; st<<=1){
            #pragma unroll
            for (int r=0;r<4;++r) pm[r] = fmaxf(pm[r], __shfl_xor(pm[r], st));
        }
        float sc[4], rs[4];
        #pragma unroll
        for (int r=0;r<4;++r){
            const float mn = fmaxf(m4[r], pm[r]);
            sc[r] = __expf(m4[r] - mn);
            m4[r] = mn;
            rs[r] = 0.f;
        }
        #pragma unroll
        for (int nb=0;nb<4;++nb){
            #pragma unroll
            for (int r=0;r<4;++r){
                const float e = __expf(S[nb][r] - m4[r]);
                S[nb][r] = e;
                rs[r] += e;
            }
        }
        #pragma unroll
        for (int st=1; st<16; st<<=1){
            #pragma unroll
            for (int r=0;r<4;++r) rs[r] += __shfl_xor(rs[r], st);
        }
        #pragma unroll
        for (int r=0;r<4;++r) l4[r] = l4[r]*sc[r] + rs[r];
        #pragma unroll
        for (int nb=0;nb<4;++nb){
            #pragma unroll
            for (int r=0;r<4;++r) PY[nb][r] *= sc[r];
        }
        // write P (bf16) to LDS — wave-local rows, no barrier needed
        #pragma unroll
        for (int r=0;r<4;++r){
            #pragma unroll
            for (int nb=0;nb<4;++nb)
                *(unsigned short*)(RBp + pwA2[r][nb]) = f2bf(S[nb][r]);
        }
        // PV: PY += P @ y_tile^T  (B = natural yt layout)
        bf16x8 pa0 = *(const bf16x8*)(RBp + paA[0]);
        bf16x8 pa1 = *(const bf16x8*)(RBp + paA[1]);
        #pragma unroll
        for (int nb=0;nb<4;++nb){
            f32x4 acc = PY[nb];
            acc = MFMA(pa0, *(const bf16x8*)(RBp + YT0 + rA[nb][0]), acc);
            acc = MFMA(pa1, *(const bf16x8*)(RBp + YT0 + rA[nb][1]), acc);
            PY[nb] = acc;
        }
        __syncthreads();   // all reads of yt/ytT done before next staging
    };

    for (int jt = 0; jt < 64; jt += 2) {
        tile_body(jt,   ra0, ra1, rb0, rb1);
        tile_body(jt+1, rb0, rb1, ra0, ra1);
    }

    // ---- epilogue: PYn (bf16) -> P region; out = gamma*(Wv@PYn^T + bv) + x
    float inv[4];
    #pragma unroll
    for (int r=0;r<4;++r) inv[r] = 1.0f / l4[r];
    #pragma unroll
    for (int r=0;r<4;++r){
        #pragma unroll
        for (int nb=0;nb<4;++nb)
            *(unsigned short*)(RBp + pwA2[r][nb]) = f2bf(PY[nb][r] * inv[r]);
    }
    __syncthreads();

    {
        const int mc = (w & 3) * 16;          // c block
        const int tbase = (w >> 2) * 64;      // t half
        bf16x8 wvA[2];
        #pragma unroll
        for (int kc=0; kc<2; ++kc){
            const float* wr = Wv + (mc + l15)*64 + kc*32 + u*8;
            const float4 f0 = *(const float4*)(wr);
            const float4 f1 = *(const float4*)(wr + 4);
            bf16x8 t;
            t[0]=(short)f2bf(f0.x); t[1]=(short)f2bf(f0.y);
            t[2]=(short)f2bf(f0.z); t[3]=(short)f2bf(f0.w);
            t[4]=(short)f2bf(f1.x); t[5]=(short)f2bf(f1.y);
            t[6]=(short)f2bf(f1.z); t[7]=(short)f2bf(f1.w);
            wvA[kc] = t;
        }
        f32x4 O[4];
        #pragma unroll
        for (int nb2=0; nb2<4; ++nb2){
            f32x4 o = (f32x4){0.f,0.f,0.f,0.f};
            const int trow = tbase + nb2*16 + l15;
            o = MFMA(wvA[0], *(const bf16x8*)(RBp + P0 + swzaddr(trow, u)), o);
            o = MFMA(wvA[1], *(const bf16x8*)(RBp + P0 + swzaddr(trow, 4 + u)), o);
            O[nb2] = o;
        }
        const float g = gammap[0];
        #pragma unroll
        for (int r=0;r<4;++r){
            const int c = mc + u*4 + r;
            const float bvc = bv[c];
            #pragma unroll
            for (int nb2=0; nb2<4; ++nb2){
                const int t = tbase + nb2*16 + l15;
                const size_t oi = (size_t)b*Cc*Nn + (size_t)c*Nn + p0 + t;
                out[oi] = g*(O[nb2][r] + bvc) + x[oi];
            }
        }
    }
}

extern "C" void kernel_launch(void* const* d_in, const int* in_sizes, int n_in,
                              void* d_out, int out_size, void* d_ws, size_t ws_size,
                              hipStream_t stream) {
    const float* x  = (const float*)d_in[0];
    const float* y  = (const float*)d_in[1];
    const float* Wq = (const float*)d_in[2];
    const float* bq = (const float*)d_in[3];
    const float* Wk = (const float*)d_in[4];
    const float* bk = (const float*)d_in[5];
    const float* Wv = (const float*)d_in[6];
    const float* bv = (const float*)d_in[7];
    const float* g  = (const float*)d_in[8];
    float* outp = (float*)d_out;
    dim3 grid(Bb * 32), block(512);
    hipLaunchKernelGGL(fused_attn_mfma, grid, block, 0, stream,
                       x, y, Wq, bq, Wk, bk, Wv, bv, g, outp);
}

// Round 4
// 221.201 us; speedup vs baseline: 2.9325x; 1.0139x over previous
//
#include <hip/hip_runtime.h>
#include <math.h>

#define Bb 8
#define Cc 64
#define Nn 4096
#define LOG2E 1.4426950408889634f
#define DEFER_TH 8.0f

typedef __attribute__((ext_vector_type(8))) short bf16x8;
typedef __attribute__((ext_vector_type(4))) float f32x4;
typedef __attribute__((ext_vector_type(4))) int   i32x4;

#define MFMA(a,b,c) __builtin_amdgcn_mfma_f32_16x16x32_bf16((a),(b),(c),0,0,0)

#if __has_builtin(__builtin_amdgcn_exp2f)
#define EXP2F(x) __builtin_amdgcn_exp2f(x)
#else
#define EXP2F(x) exp2f(x)
#endif

__device__ __forceinline__ unsigned short f2bf(float f){
    unsigned uu = __float_as_uint(f);
    return (unsigned short)((uu + 0x7FFFu + ((uu>>16)&1u)) >> 16);
}
__device__ __forceinline__ float bfres(float f, unsigned short h){
    return f - __uint_as_float(((unsigned)h)<<16);
}
// byte address of a 16B slot in a 128B row, XOR-swizzled (bank balance)
__device__ __forceinline__ int swzaddr(int row, int slot){
    int h = (row ^ (row>>3)) & 7;
    return row*128 + (((slot ^ h)&7)<<4);
}

// ---------------- kernel 1: q = Wq@x + bq  (hi/lo-split MFMA, bf16 out to ws)
__global__ __launch_bounds__(256) void precompute_q(
    const float* __restrict__ x, const float* __restrict__ Wq,
    const float* __restrict__ bq, unsigned short* __restrict__ wsq)
{
    __shared__ __align__(16) unsigned char XHI[16384];  // x^T hi [128p][64cx] bf16
    __shared__ __align__(16) unsigned char XLO[16384];  // x^T lo
    const int tid = threadIdx.x;
    const int l   = tid & 63;
    const int w   = tid >> 6;
    const int l15 = l & 15;
    const int u   = l >> 4;
    const int b   = blockIdx.x & 7;          // XCD-friendly: batch per XCD
    const int pt  = blockIdx.x >> 3;         // 0..31
    const int p0  = pt*128;

    // A-fragments from Wq rows c = 16w + l15 (hi/lo split)
    bf16x8 whiA[2], wloA[2];
    #pragma unroll
    for (int kc=0; kc<2; ++kc){
        const float* wr = Wq + (16*w + l15)*64 + kc*32 + u*8;
        const float4 f0 = *(const float4*)(wr);
        const float4 f1 = *(const float4*)(wr + 4);
        const float vv[8] = {f0.x,f0.y,f0.z,f0.w,f1.x,f1.y,f1.z,f1.w};
        bf16x8 hi, lo;
        #pragma unroll
        for (int i=0;i<8;++i){
            const unsigned short h = f2bf(vv[i]);
            hi[i] = (short)h;
            lo[i] = (short)f2bf(bfres(vv[i], h));
        }
        whiA[kc]=hi; wloA[kc]=lo;
    }
    // stage x^T (hi/lo) for p-tile: thread handles 2 cx rows x 16 p
    {
        const int cx0 = (tid & 31)*2;
        const int pq  = (tid >> 5)*16;
        const float* xr0 = x + ((size_t)b*64 + cx0)*4096 + p0 + pq;
        const float* xr1 = xr0 + 4096;
        #pragma unroll
        for (int q4=0; q4<4; ++q4){
            const float4 a = *(const float4*)(xr0 + q4*4);
            const float4 c = *(const float4*)(xr1 + q4*4);
            const float av[4]={a.x,a.y,a.z,a.w}, cv[4]={c.x,c.y,c.z,c.w};
            #pragma unroll
            for (int k=0;k<4;++k){
                const int p = pq + q4*4 + k;
                const unsigned short h0=f2bf(av[k]), h1=f2bf(cv[k]);
                const unsigned short l0=f2bf(bfres(av[k],h0));
                const unsigned short l1=f2bf(bfres(cv[k],h1));
                const int ad = swzaddr(p, cx0>>3) + (cx0&7)*2;
                *(unsigned int*)(XHI + ad) = (unsigned)h0 | ((unsigned)h1<<16);
                *(unsigned int*)(XLO + ad) = (unsigned)l0 | ((unsigned)l1<<16);
            }
        }
    }
    __syncthreads();

    f32x4 D[8];
    #pragma unroll
    for (int nb=0;nb<8;++nb) D[nb]=(f32x4){0.f,0.f,0.f,0.f};
    #pragma unroll
    for (int nb=0;nb<8;++nb){
        #pragma unroll
        for (int kc=0;kc<2;++kc){
            const int ad = swzaddr(16*nb + l15, kc*4 + u);
            const bf16x8 xh = *(const bf16x8*)(XHI + ad);
            const bf16x8 xl = *(const bf16x8*)(XLO + ad);
            D[nb] = MFMA(whiA[kc], xh, D[nb]);
            D[nb] = MFMA(whiA[kc], xl, D[nb]);
            D[nb] = MFMA(wloA[kc], xh, D[nb]);
        }
    }
    float bq4[4];
    #pragma unroll
    for (int r=0;r<4;++r) bq4[r] = bq[16*w + u*4 + r];
    #pragma unroll
    for (int nb=0;nb<8;++nb){
        #pragma unroll
        for (int r=0;r<4;++r){
            const int c = 16*w + u*4 + r;
            const int p = p0 + 16*nb + l15;
            wsq[((size_t)b*64 + c)*4096 + p] = f2bf(D[nb][r] + bq4[r]);
        }
    }
}

// ---------------- kernel 2: fused flash attention (MFMA), 4 waves/WG, 2 WG/CU
__global__ __launch_bounds__(256,2) void fused_attn2(
    const float* __restrict__ x, const float* __restrict__ y,
    const float* __restrict__ Wk, const unsigned short* __restrict__ wsq,
    const float* __restrict__ Wv, const float* __restrict__ bv,
    const float* __restrict__ gammap, float* __restrict__ out)
{
    __shared__ __align__(16) unsigned char QW [8192];      // qw [64t][64ci] bf16 swz
    __shared__ __align__(16) unsigned char PT [8192];      // P / PYn [64t][64] bf16 swz
    __shared__ __align__(16) unsigned char WKT[8192];      // Wk^T [64ci][64c] bf16 swz (phase A)
    __shared__ __align__(16) unsigned char YN [2][8192];   // y tile natural [ci][j]
    __shared__ __align__(16) unsigned char YT [2][8192];   // y tile transposed [j][ci]

    const int tid = threadIdx.x;
    const int l   = tid & 63;
    const int w   = tid >> 6;          // wave 0..3; owns t rows [16w,16w+16)
    const int l15 = l & 15;
    const int u   = l >> 4;
    const int b   = blockIdx.x & 7;    // XCD keeps one batch's y in L2
    const int blk = blockIdx.x >> 3;   // 0..63
    const int p0  = blk*64;

    const float* __restrict__ yb = y + (size_t)b*Cc*Nn;

    // staging map: thread -> (ci row, 16 j)
    const int sci = tid >> 2;
    const int sj0 = (tid & 3) * 16;

    // 0. issue tile-0 global prefetch ASAP
    float4 pf0, pf1, pf2, pf3;
    {
        const float* yr = yb + (size_t)sci*Nn + sj0;
        pf0 = *(const float4*)(yr);
        pf1 = *(const float4*)(yr + 4);
        pf2 = *(const float4*)(yr + 8);
        pf3 = *(const float4*)(yr + 12);
    }

    // 1. stage Wk^T bf16 (thread: row c = tid>>2, 16 ci)
    {
        const int c   = tid >> 2;
        const int ci0 = (tid & 3)*16;
        const float* wr = Wk + c*64 + ci0;
        #pragma unroll
        for (int q4=0; q4<4; ++q4){
            const float4 f = *(const float4*)(wr + q4*4);
            const float fv[4] = {f.x,f.y,f.z,f.w};
            #pragma unroll
            for (int k=0;k<4;++k){
                const int ci = ci0 + q4*4 + k;
                *(unsigned short*)(WKT + swzaddr(ci, c>>3) + (c&7)*2) = f2bf(fv[k]);
            }
        }
    }
    // 2. Qb A-fragments straight from ws (16B aligned chunks)
    bf16x8 qA[2];
    {
        const unsigned short* qchan = wsq + ((size_t)b*64 + blk)*4096;
        #pragma unroll
        for (int kc=0;kc<2;++kc)
            qA[kc] = *(const bf16x8*)(qchan + 64*(16*w + l15) + kc*32 + u*8);
    }
    __syncthreads();

    // 3. qw = Qb @ Wk  (scaled by log2e), write to QW, read back A-frags
    {
        f32x4 D2[4];
        #pragma unroll
        for (int nb=0;nb<4;++nb){
            f32x4 d = (f32x4){0.f,0.f,0.f,0.f};
            d = MFMA(qA[0], *(const bf16x8*)(WKT + swzaddr(16*nb + l15, u)),     d);
            d = MFMA(qA[1], *(const bf16x8*)(WKT + swzaddr(16*nb + l15, 4 + u)), d);
            D2[nb] = d;
        }
        #pragma unroll
        for (int nb=0;nb<4;++nb){
            #pragma unroll
            for (int r=0;r<4;++r){
                const int t  = 16*w + u*4 + r;
                const int ci = 16*nb + l15;
                *(unsigned short*)(QW + swzaddr(t, 2*nb + (l15>>3)) + (l15&7)*2)
                    = f2bf(D2[nb][r] * LOG2E);
            }
        }
    }
    bf16x8 qwA[2];
    qwA[0] = *(const bf16x8*)(QW + swzaddr(16*w + l15, u));
    qwA[1] = *(const bf16x8*)(QW + swzaddr(16*w + l15, 4 + u));

    // precomputed loop-invariant LDS offsets
    int rd[4][2];            // B-frag reads: rows 16nb+l15, slots kc*4+u (YT, YN, PT)
    #pragma unroll
    for (int nb=0;nb<4;++nb){
        rd[nb][0] = swzaddr(16*nb + l15, u);
        rd[nb][1] = swzaddr(16*nb + l15, 4 + u);
    }
    const int paA0 = swzaddr(16*w + l15, u);        // P A-frag
    const int paA1 = swzaddr(16*w + l15, 4 + u);
    int pw[4][4];            // P writes: row 16w+u*4+r, col 16nb+l15
    #pragma unroll
    for (int r=0;r<4;++r)
        #pragma unroll
        for (int nb=0;nb<4;++nb)
            pw[r][nb] = swzaddr(16*w + u*4 + r, 2*nb + (l15>>3)) + (l15&7)*2;

    // stage helper: convert 16 f32 -> bf16, write natural + transposed layouts
    auto stage_write = [&](float4 a0, float4 a1, float4 a2, float4 a3, int buf){
        const float v[16] = {a0.x,a0.y,a0.z,a0.w, a1.x,a1.y,a1.z,a1.w,
                             a2.x,a2.y,a2.z,a2.w, a3.x,a3.y,a3.z,a3.w};
        unsigned short e[16];
        #pragma unroll
        for (int k=0;k<16;++k) e[k] = f2bf(v[k]);
        i32x4 pk0, pk1;
        pk0.x = (int)((unsigned)e[0]  | ((unsigned)e[1]<<16));
        pk0.y = (int)((unsigned)e[2]  | ((unsigned)e[3]<<16));
        pk0.z = (int)((unsigned)e[4]  | ((unsigned)e[5]<<16));
        pk0.w = (int)((unsigned)e[6]  | ((unsigned)e[7]<<16));
        pk1.x = (int)((unsigned)e[8]  | ((unsigned)e[9]<<16));
        pk1.y = (int)((unsigned)e[10] | ((unsigned)e[11]<<16));
        pk1.z = (int)((unsigned)e[12] | ((unsigned)e[13]<<16));
        pk1.w = (int)((unsigned)e[14] | ((unsigned)e[15]<<16));
        *(i32x4*)(YN[buf] + swzaddr(sci, (sj0>>3)))     = pk0;
        *(i32x4*)(YN[buf] + swzaddr(sci, (sj0>>3) + 1)) = pk1;
        #pragma unroll
        for (int k=0;k<16;++k)
            *(unsigned short*)(YT[buf] + swzaddr(sj0 + k, sci>>3) + (sci&7)*2) = e[k];
    };

    // prologue: write tile 0
    stage_write(pf0, pf1, pf2, pf3, 0);
    __syncthreads();

    // flash state
    f32x4 PY[4];
    #pragma unroll
    for (int nb=0;nb<4;++nb) PY[nb] = (f32x4){0.f,0.f,0.f,0.f};
    float m4[4], l4[4];
    #pragma unroll
    for (int r=0;r<4;++r){ m4[r] = -1.0e30f; l4[r] = 0.f; }

    for (int jt = 0; jt < 64; ++jt){
        const int cur = jt & 1;
        // prefetch next tile into regs (latency hidden under S+softmax+PV)
        float4 n0,n1,n2,n3;
        if (jt < 63){
            const float* yr = yb + (size_t)sci*Nn + (jt+1)*64 + sj0;
            n0 = *(const float4*)(yr);
            n1 = *(const float4*)(yr + 4);
            n2 = *(const float4*)(yr + 8);
            n3 = *(const float4*)(yr + 12);
        }
        // S = (log2e*qw) @ y_tile
        f32x4 S[4];
        #pragma unroll
        for (int nb=0;nb<4;++nb){
            f32x4 s = (f32x4){0.f,0.f,0.f,0.f};
            s = MFMA(qwA[0], *(const bf16x8*)(YT[cur] + rd[nb][0]), s);
            s = MFMA(qwA[1], *(const bf16x8*)(YT[cur] + rd[nb][1]), s);
            S[nb] = s;
        }
        // online softmax (base-2), defer-max
        float pm[4];
        #pragma unroll
        for (int r=0;r<4;++r)
            pm[r] = fmaxf(fmaxf(S[0][r],S[1][r]), fmaxf(S[2][r],S[3][r]));
        #pragma unroll
        for (int st=1; st<16; st<<=1){
            #pragma unroll
            for (int r=0;r<4;++r) pm[r] = fmaxf(pm[r], __shfl_xor(pm[r], st));
        }
        bool need = false;
        #pragma unroll
        for (int r=0;r<4;++r) need = need || (pm[r] > m4[r] + DEFER_TH);
        if (__ballot(need)) {
            #pragma unroll
            for (int r=0;r<4;++r){
                const float mn = fmaxf(m4[r], pm[r]);
                const float sc = EXP2F(m4[r] - mn);
                m4[r] = mn;
                l4[r] *= sc;
                #pragma unroll
                for (int nb=0;nb<4;++nb) PY[nb][r] *= sc;
            }
        }
        float rs[4] = {0.f,0.f,0.f,0.f};
        #pragma unroll
        for (int nb=0;nb<4;++nb){
            #pragma unroll
            for (int r=0;r<4;++r){
                const float e = EXP2F(S[nb][r] - m4[r]);
                S[nb][r] = e;
                rs[r] += e;
            }
        }
        #pragma unroll
        for (int st=1; st<16; st<<=1){
            #pragma unroll
            for (int r=0;r<4;++r) rs[r] += __shfl_xor(rs[r], st);
        }
        #pragma unroll
        for (int r=0;r<4;++r) l4[r] += rs[r];

        // P -> LDS (wave-local rows; lgkm ordering by compiler)
        #pragma unroll
        for (int r=0;r<4;++r)
            #pragma unroll
            for (int nb=0;nb<4;++nb)
                *(unsigned short*)(PT + pw[r][nb]) = f2bf(S[nb][r]);
        // PV: PY += P @ y_tile^T
        {
            const bf16x8 pa0 = *(const bf16x8*)(PT + paA0);
            const bf16x8 pa1 = *(const bf16x8*)(PT + paA1);
            #pragma unroll
            for (int nb=0;nb<4;++nb){
                f32x4 acc = PY[nb];
                acc = MFMA(pa0, *(const bf16x8*)(YN[cur] + rd[nb][0]), acc);
                acc = MFMA(pa1, *(const bf16x8*)(YN[cur] + rd[nb][1]), acc);
                PY[nb] = acc;
            }
        }
        // stage next tile into other buffer
        if (jt < 63) stage_write(n0, n1, n2, n3, cur ^ 1);
        __syncthreads();
    }

    // epilogue: normalized PY -> PT; out = gamma*(Wv @ PYn^T + bv) + x
    float inv[4];
    #pragma unroll
    for (int r=0;r<4;++r) inv[r] = 1.0f / l4[r];
    #pragma unroll
    for (int r=0;r<4;++r)
        #pragma unroll
        for (int nb=0;nb<4;++nb)
            *(unsigned short*)(PT + pw[r][nb]) = f2bf(PY[nb][r] * inv[r]);
    __syncthreads();

    {
        bf16x8 wvA[2];
        #pragma unroll
        for (int kc=0;kc<2;++kc){
            const float* wr = Wv + (16*w + l15)*64 + kc*32 + u*8;
            const float4 f0 = *(const float4*)(wr);
            const float4 f1 = *(const float4*)(wr + 4);
            const float vv[8] = {f0.x,f0.y,f0.z,f0.w,f1.x,f1.y,f1.z,f1.w};
            bf16x8 t;
            #pragma unroll
            for (int i=0;i<8;++i) t[i] = (short)f2bf(vv[i]);
            wvA[kc] = t;
        }
        f32x4 O[4];
        #pragma unroll
        for (int nb=0;nb<4;++nb){
            f32x4 o = (f32x4){0.f,0.f,0.f,0.f};
            o = MFMA(wvA[0], *(const bf16x8*)(PT + rd[nb][0]), o);
            o = MFMA(wvA[1], *(const bf16x8*)(PT + rd[nb][1]), o);
            O[nb] = o;
        }
        const float g = gammap[0];
        #pragma unroll
        for (int r=0;r<4;++r){
            const int cout = 16*w + u*4 + r;
            const float bvc = bv[cout];
            #pragma unroll
            for (int nb=0;nb<4;++nb){
                const int t = 16*nb + l15;
                const size_t oi = ((size_t)b*64 + cout)*4096 + p0 + t;
                out[oi] = g*(O[nb][r] + bvc) + x[oi];
            }
        }
    }
}

extern "C" void kernel_launch(void* const* d_in, const int* in_sizes, int n_in,
                              void* d_out, int out_size, void* d_ws, size_t ws_size,
                              hipStream_t stream) {
    const float* x  = (const float*)d_in[0];
    const float* y  = (const float*)d_in[1];
    const float* Wq = (const float*)d_in[2];
    const float* bq = (const float*)d_in[3];
    const float* Wk = (const float*)d_in[4];
    // d_in[5] = bk: mathematically dead (constant along softmax axis)
    const float* Wv = (const float*)d_in[6];
    const float* bv = (const float*)d_in[7];
    const float* g  = (const float*)d_in[8];
    float* outp = (float*)d_out;
    unsigned short* wsq = (unsigned short*)d_ws;   // q bf16: 8*64*4096*2B = 4MB

    hipLaunchKernelGGL(precompute_q, dim3(256), dim3(256), 0, stream,
                       x, Wq, bq, wsq);
    hipLaunchKernelGGL(fused_attn2, dim3(512), dim3(256), 0, stream,
                       x, y, Wk, wsq, Wv, bv, g, outp);
}

// Round 5
// 180.598 us; speedup vs baseline: 3.5918x; 1.2248x over previous
//
#include <hip/hip_runtime.h>
#include <math.h>

#define LOG2E 1.4426950408889634f
#define DEFER_TH 8.0f

typedef __attribute__((ext_vector_type(8)))  short bf16x8;
typedef __attribute__((ext_vector_type(4)))  short bf16x4;
typedef __attribute__((ext_vector_type(4)))  float f32x4;
typedef __attribute__((ext_vector_type(16))) float f32x16;
typedef __attribute__((ext_vector_type(4)))  int   i32x4;

#define MFMA16(a,b,c) __builtin_amdgcn_mfma_f32_16x16x32_bf16((a),(b),(c),0,0,0)
#define MFMA32(a,b,c) __builtin_amdgcn_mfma_f32_32x32x16_bf16((a),(b),(c),0,0,0)

#if __has_builtin(__builtin_amdgcn_exp2f)
#define EXP2F(v) __builtin_amdgcn_exp2f(v)
#else
#define EXP2F(v) exp2f(v)
#endif

__device__ __forceinline__ unsigned short f2bf(float f){     // RTNE
    unsigned uu = __float_as_uint(f);
    return (unsigned short)((uu + 0x7FFFu + ((uu>>16)&1u)) >> 16);
}
__device__ __forceinline__ float bfres(float f, unsigned short h){
    return f - __uint_as_float(((unsigned)h)<<16);
}
__device__ __forceinline__ unsigned packrn(float a, float b){ // round-half-up pack (lo=a)
    unsigned ua = (__float_as_uint(a) + 0x8000u) >> 16;
    unsigned ub = (__float_as_uint(b) + 0x8000u) & 0xFFFF0000u;
    return ua | ub;
}
__device__ __forceinline__ unsigned packne(float a, float b){ // RTNE pack
    return (unsigned)f2bf(a) | ((unsigned)f2bf(b) << 16);
}
// 128B rows, 16B slots, XOR swizzle: ≤2-way on all access patterns used here
__device__ __forceinline__ int lds_rc(int row, int slot){
    int h = (row ^ (row >> 3)) & 7;
    return (row << 7) + (((slot ^ h) & 7) << 4);
}
union U4 { unsigned u[4]; bf16x8 v; i32x4 i; };

// ---------------- kernel 1: q = Wq@x + bq  (hi/lo-split MFMA -> bf16 ws)
__global__ __launch_bounds__(256) void precompute_q(
    const float* __restrict__ x, const float* __restrict__ Wq,
    const float* __restrict__ bq, unsigned short* __restrict__ wsq)
{
    __shared__ __align__(16) unsigned char XHI[16384];  // x^T [128p][64cx] bf16 hi, swz
    __shared__ __align__(16) unsigned char XLO[16384];  // lo residual
    const int tid = threadIdx.x;
    const int l15 = tid & 15;
    const int u   = (tid & 63) >> 4;
    const int w   = tid >> 6;
    const int b   = blockIdx.x & 7;
    const int pt  = blockIdx.x >> 3;
    const int p0  = pt * 128;

    // Wq A-frags (rows c = 16w + l15), hi/lo split
    bf16x8 whiA[2], wloA[2];
    #pragma unroll
    for (int kc=0; kc<2; ++kc){
        const float* wr = Wq + (16*w + l15)*64 + kc*32 + u*8;
        const float4 f0 = *(const float4*)(wr);
        const float4 f1 = *(const float4*)(wr + 4);
        const float vv[8] = {f0.x,f0.y,f0.z,f0.w,f1.x,f1.y,f1.z,f1.w};
        bf16x8 hi, lo;
        #pragma unroll
        for (int i=0;i<8;++i){
            const unsigned short h = f2bf(vv[i]);
            hi[i] = (short)h;
            lo[i] = (short)f2bf(bfres(vv[i], h));
        }
        whiA[kc]=hi; wloA[kc]=lo;
    }
    // stage x^T: thread = (p, 32-cx half); strided coalesced global reads, b128 LDS writes
    {
        const int p  = tid & 127;
        const int hf = tid >> 7;
        const float* xr = x + ((size_t)(b*64 + hf*32))*4096 + p0 + p;
        float v[32];
        #pragma unroll
        for (int k2=0;k2<32;++k2) v[k2] = xr[(size_t)k2*4096];
        unsigned hiw[16], low[16];
        #pragma unroll
        for (int q2=0;q2<16;++q2){
            const unsigned short h0 = f2bf(v[2*q2]),  h1 = f2bf(v[2*q2+1]);
            const unsigned short r0 = f2bf(bfres(v[2*q2],h0)), r1 = f2bf(bfres(v[2*q2+1],h1));
            hiw[q2] = (unsigned)h0 | ((unsigned)h1<<16);
            low[q2] = (unsigned)r0 | ((unsigned)r1<<16);
        }
        #pragma unroll
        for (int s=0;s<4;++s){
            i32x4 a = {(int)hiw[4*s],(int)hiw[4*s+1],(int)hiw[4*s+2],(int)hiw[4*s+3]};
            i32x4 c2= {(int)low[4*s],(int)low[4*s+1],(int)low[4*s+2],(int)low[4*s+3]};
            *(i32x4*)(XHI + lds_rc(p, hf*4 + s)) = a;
            *(i32x4*)(XLO + lds_rc(p, hf*4 + s)) = c2;
        }
    }
    __syncthreads();

    f32x4 D[8];
    #pragma unroll
    for (int nb=0;nb<8;++nb) D[nb] = (f32x4){0.f,0.f,0.f,0.f};
    #pragma unroll
    for (int nb=0;nb<8;++nb){
        #pragma unroll
        for (int kc=0;kc<2;++kc){
            const int ad = lds_rc(16*nb + l15, 4*kc + u);
            const bf16x8 xh = *(const bf16x8*)(XHI + ad);
            const bf16x8 xl = *(const bf16x8*)(XLO + ad);
            D[nb] = MFMA16(whiA[kc], xh, D[nb]);
            D[nb] = MFMA16(whiA[kc], xl, D[nb]);
            D[nb] = MFMA16(wloA[kc], xh, D[nb]);
        }
    }
    float bq4[4];
    #pragma unroll
    for (int r=0;r<4;++r) bq4[r] = bq[16*w + u*4 + r];
    #pragma unroll
    for (int nb=0;nb<8;++nb){
        #pragma unroll
        for (int r=0;r<4;++r)
            wsq[((size_t)b*64 + 16*w + u*4 + r)*4096 + p0 + 16*nb + l15]
                = f2bf(D[nb][r] + bq4[r]);
    }
}

// ---------------- kernel 2: fused flash attention, swapped-QK^T 32x32, reg-resident P
__global__ __launch_bounds__(256, 1) void fused_attn3(
    const float* __restrict__ x, const float* __restrict__ y,
    const float* __restrict__ Wk, const unsigned short* __restrict__ wsq,
    const float* __restrict__ Wv, const float* __restrict__ bv,
    const float* __restrict__ gammap, float* __restrict__ out)
{
    __shared__ __align__(16) unsigned char YN[2][8192];   // y tile natural [64ci][64j] bf16 swz
    __shared__ __align__(16) unsigned char YT[2][8192];   // y tile transposed [64j][64ci]

    const int tid = threadIdx.x;
    const int l   = tid & 63;
    const int w   = tid >> 6;          // wave 0..3 owns t in [32w, 32w+32)
    const int l31 = l & 31;
    const int g   = l >> 5;
    const int b   = blockIdx.x & 7;
    const int pb  = blockIdx.x >> 3;   // 0..31
    const int n0  = pb * 128;

    const float* __restrict__ yb = y + (size_t)b*64*4096;

    // ---- phase A: qw^T = Wk^T @ Qb^T via MFMA; assemble 4 register B-frags (x LOG2E)
    f32x16 QC0, QC1;
    #pragma unroll
    for (int i=0;i<16;++i){ QC0[i]=0.f; QC1[i]=0.f; }
    {
        const int ch  = (pb*2) + (w >> 1);
        const unsigned short* qrow = wsq + ((size_t)b*64 + ch)*4096 + ((w&1)*32 + l31)*64;
        #pragma unroll
        for (int kc=0;kc<4;++kc){
            const bf16x8 qb = *(const bf16x8*)(qrow + 16*kc + g*8);
            #pragma unroll
            for (int rowb=0;rowb<2;++rowb){
                bf16x8 wa;
                #pragma unroll
                for (int i=0;i<8;++i)
                    wa[i] = (short)f2bf(Wk[(16*kc + g*8 + i)*64 + 32*rowb + l31]);
                if (rowb==0) QC0 = MFMA32(wa, qb, QC0);
                else         QC1 = MFMA32(wa, qb, QC1);
            }
        }
    }
    bf16x8 qwB[4];
    {
        unsigned qp[2][8], qq[2][8];
        #pragma unroll
        for (int m=0;m<8;++m){
            qp[0][m] = packne(QC0[2*m]*LOG2E, QC0[2*m+1]*LOG2E);
            qp[1][m] = packne(QC1[2*m]*LOG2E, QC1[2*m+1]*LOG2E);
        }
        #pragma unroll
        for (int rb=0;rb<2;++rb)
            #pragma unroll
            for (int m=0;m<8;++m) qq[rb][m] = __shfl_xor((int)qp[rb][m], 32);
        #pragma unroll
        for (int kc=0;kc<4;++kc){
            const int rb = kc>>1, h = kc&1;
            U4 uu;
            if (g==0){ uu.u[0]=qp[rb][4*h+0]; uu.u[1]=qp[rb][4*h+1];
                       uu.u[2]=qq[rb][4*h+0]; uu.u[3]=qq[rb][4*h+1]; }
            else     { uu.u[0]=qq[rb][4*h+2]; uu.u[1]=qq[rb][4*h+3];
                       uu.u[2]=qp[rb][4*h+2]; uu.u[3]=qp[rb][4*h+3]; }
            qwB[kc] = uu.v;
        }
    }

    // ---- loop-invariant addresses
    const int nci = tid >> 2, njq = tid & 3;    // natural staging: (ci row, 16 j)
    const int tj  = tid & 63, tcq = tid >> 6;   // transposed staging: (j row, 16 ci)
    const int wnat0 = lds_rc(nci, njq*2),     wnat1 = lds_rc(nci, njq*2 + 1);
    const int wtr0  = lds_rc(tj,  tcq*2),     wtr1  = lds_rc(tj,  tcq*2 + 1);
    int rS[2][4];
    #pragma unroll
    for (int jb=0;jb<2;++jb)
        #pragma unroll
        for (int kc=0;kc<4;++kc) rS[jb][kc] = lds_rc(32*jb + l31, 2*kc + g);
    int rPa[2][4][2];
    #pragma unroll
    for (int cib=0;cib<2;++cib)
        #pragma unroll
        for (int kcp=0;kcp<4;++kcp){
            const int jb = kcp>>1, h = kcp&1;
            rPa[cib][kcp][0] = lds_rc(l31 + 32*cib, 4*jb + 2*h)     + 8*g;
            rPa[cib][kcp][1] = lds_rc(l31 + 32*cib, 4*jb + 2*h + 1) + 8*g;
        }
    const float* gnat = yb + (size_t)nci*4096 + njq*16;
    const float* gtr  = yb + (size_t)(tcq*16)*4096 + tj;

    // ---- flash state (lane owns query t = n0 + 32w + l31; partner lane l^32 shares it)
    f32x16 OC0, OC1;
    #pragma unroll
    for (int i=0;i<16;++i){ OC0[i]=0.f; OC1[i]=0.f; }
    float m = -1.0e30f, lsum = 0.f;

    // prologue: stage tile 0 -> buf0
    {
        float4 a0 = *(const float4*)(gnat);
        float4 a1 = *(const float4*)(gnat + 4);
        float4 a2 = *(const float4*)(gnat + 8);
        float4 a3 = *(const float4*)(gnat + 12);
        float tv[16];
        #pragma unroll
        for (int k2=0;k2<16;++k2) tv[k2] = gtr[(size_t)k2*4096];
        const float nvv[16] = {a0.x,a0.y,a0.z,a0.w,a1.x,a1.y,a1.z,a1.w,
                               a2.x,a2.y,a2.z,a2.w,a3.x,a3.y,a3.z,a3.w};
        unsigned nk[8], tk[8];
        #pragma unroll
        for (int q2=0;q2<8;++q2){ nk[q2]=packrn(nvv[2*q2],nvv[2*q2+1]);
                                  tk[q2]=packrn(tv[2*q2], tv[2*q2+1]); }
        i32x4 w0={(int)nk[0],(int)nk[1],(int)nk[2],(int)nk[3]};
        i32x4 w1={(int)nk[4],(int)nk[5],(int)nk[6],(int)nk[7]};
        i32x4 w2={(int)tk[0],(int)tk[1],(int)tk[2],(int)tk[3]};
        i32x4 w3={(int)tk[4],(int)tk[5],(int)tk[6],(int)tk[7]};
        *(i32x4*)(YN[0] + wnat0) = w0;  *(i32x4*)(YN[0] + wnat1) = w1;
        *(i32x4*)(YT[0] + wtr0)  = w2;  *(i32x4*)(YT[0] + wtr1)  = w3;
    }
    __syncthreads();

    for (int jt = 0; jt < 64; ++jt){
        const int cur = jt & 1;
        const bool pf = (jt < 63);
        // prefetch next tile into regs (hidden under MFMA/softmax)
        float4 a0,a1,a2,a3; float tv[16];
        if (pf){
            const float* gn = gnat + (jt+1)*64;
            a0 = *(const float4*)(gn);     a1 = *(const float4*)(gn + 4);
            a2 = *(const float4*)(gn + 8); a3 = *(const float4*)(gn + 12);
            const float* gt = gtr + (jt+1)*64;
            #pragma unroll
            for (int k2=0;k2<16;++k2) tv[k2] = gt[(size_t)k2*4096];
        }
        // S^T = mfma(A=yT, B=qw) : lane holds col t, rows j
        f32x16 SC0, SC1;
        #pragma unroll
        for (int i=0;i<16;++i){ SC0[i]=0.f; SC1[i]=0.f; }
        #pragma unroll
        for (int kc=0;kc<4;++kc){
            SC0 = MFMA32(*(const bf16x8*)(YT[cur] + rS[0][kc]), qwB[kc], SC0);
            SC1 = MFMA32(*(const bf16x8*)(YT[cur] + rS[1][kc]), qwB[kc], SC1);
        }
        // in-lane softmax (log2 domain), partner exchange via one shfl each
        float mx[16];
        #pragma unroll
        for (int i=0;i<16;++i) mx[i] = fmaxf(SC0[i], SC1[i]);
        #pragma unroll
        for (int s=8;s>=1;s>>=1)
            #pragma unroll
            for (int i=0;i<s;++i) mx[i] = fmaxf(mx[i], mx[i+s]);
        float pm = fmaxf(mx[0], __shfl_xor(mx[0], 32));
        if (__ballot(pm > m + DEFER_TH)) {
            const float mn = fmaxf(m, pm);
            const float sc = EXP2F(m - mn);
            m = mn; lsum *= sc;
            #pragma unroll
            for (int i=0;i<16;++i){ OC0[i]*=sc; OC1[i]*=sc; }
        }
        float p0f[16], p1f[16];
        #pragma unroll
        for (int i=0;i<16;++i){ p0f[i]=EXP2F(SC0[i]-m); p1f[i]=EXP2F(SC1[i]-m); }
        float sm[16];
        #pragma unroll
        for (int i=0;i<16;++i) sm[i] = p0f[i] + p1f[i];
        #pragma unroll
        for (int s=8;s>=1;s>>=1)
            #pragma unroll
            for (int i=0;i<s;++i) sm[i] += sm[i+s];
        lsum += sm[0] + __shfl_xor(sm[0], 32);
        // pack P in-register (order = C-reg order; matched k-mapping below)
        unsigned pk0[8], pk1[8];
        #pragma unroll
        for (int q2=0;q2<8;++q2){ pk0[q2]=packrn(p0f[2*q2],p0f[2*q2+1]);
                                  pk1[q2]=packrn(p1f[2*q2],p1f[2*q2+1]); }
        // PV: O^T[ci][t] += mfma(A=ynat (permuted-j b64 pairs), B=P regs)
        #pragma unroll
        for (int kcp=0;kcp<4;++kcp){
            const int h = kcp&1;
            U4 pb4;
            if (kcp<2){ pb4.u[0]=pk0[4*h+0]; pb4.u[1]=pk0[4*h+1];
                        pb4.u[2]=pk0[4*h+2]; pb4.u[3]=pk0[4*h+3]; }
            else      { pb4.u[0]=pk1[4*h+0]; pb4.u[1]=pk1[4*h+1];
                        pb4.u[2]=pk1[4*h+2]; pb4.u[3]=pk1[4*h+3]; }
            {
                bf16x4 y0 = *(const bf16x4*)(YN[cur] + rPa[0][kcp][0]);
                bf16x4 y1 = *(const bf16x4*)(YN[cur] + rPa[0][kcp][1]);
                bf16x8 ya; 
                #pragma unroll
                for (int i=0;i<4;++i){ ya[i]=y0[i]; ya[4+i]=y1[i]; }
                OC0 = MFMA32(ya, pb4.v, OC0);
            }
            {
                bf16x4 y0 = *(const bf16x4*)(YN[cur] + rPa[1][kcp][0]);
                bf16x4 y1 = *(const bf16x4*)(YN[cur] + rPa[1][kcp][1]);
                bf16x8 ya;
                #pragma unroll
                for (int i=0;i<4;++i){ ya[i]=y0[i]; ya[4+i]=y1[i]; }
                OC1 = MFMA32(ya, pb4.v, OC1);
            }
        }
        // stage next tile
        if (pf){
            const float nvv[16] = {a0.x,a0.y,a0.z,a0.w,a1.x,a1.y,a1.z,a1.w,
                                   a2.x,a2.y,a2.z,a2.w,a3.x,a3.y,a3.z,a3.w};
            unsigned nk[8], tk[8];
            #pragma unroll
            for (int q2=0;q2<8;++q2){ nk[q2]=packrn(nvv[2*q2],nvv[2*q2+1]);
                                      tk[q2]=packrn(tv[2*q2], tv[2*q2+1]); }
            const int nxt = cur ^ 1;
            i32x4 w0={(int)nk[0],(int)nk[1],(int)nk[2],(int)nk[3]};
            i32x4 w1={(int)nk[4],(int)nk[5],(int)nk[6],(int)nk[7]};
            i32x4 w2={(int)tk[0],(int)tk[1],(int)tk[2],(int)tk[3]};
            i32x4 w3={(int)tk[4],(int)tk[5],(int)tk[6],(int)tk[7]};
            *(i32x4*)(YN[nxt] + wnat0) = w0;  *(i32x4*)(YN[nxt] + wnat1) = w1;
            *(i32x4*)(YT[nxt] + wtr0)  = w2;  *(i32x4*)(YT[nxt] + wtr1)  = w3;
        }
        __syncthreads();
    }

    // ---- epilogue: Z = Wv @ PYn^T (all-register B), out = gamma*(Z+bv) + x
    const float inv = 1.0f / lsum;
    unsigned ok0[8], ok1[8];
    #pragma unroll
    for (int q2=0;q2<8;++q2){
        ok0[q2] = packne(OC0[2*q2]*inv, OC0[2*q2+1]*inv);
        ok1[q2] = packne(OC1[2*q2]*inv, OC1[2*q2+1]*inv);
    }
    f32x16 ZC0, ZC1;
    #pragma unroll
    for (int i=0;i<16;++i){ ZC0[i]=0.f; ZC1[i]=0.f; }
    #pragma unroll
    for (int kcz=0;kcz<4;++kcz){
        const int cib = kcz>>1, h = kcz&1;
        U4 pb4;
        if (cib==0){ pb4.u[0]=ok0[4*h+0]; pb4.u[1]=ok0[4*h+1];
                     pb4.u[2]=ok0[4*h+2]; pb4.u[3]=ok0[4*h+3]; }
        else       { pb4.u[0]=ok1[4*h+0]; pb4.u[1]=ok1[4*h+1];
                     pb4.u[2]=ok1[4*h+2]; pb4.u[3]=ok1[4*h+3]; }
        const int j0c = 32*cib + 16*h + 4*g;
        #pragma unroll
        for (int rowb=0;rowb<2;++rowb){
            const float* wr = Wv + (size_t)(32*rowb + l31)*64 + j0c;
            const float4 f0 = *(const float4*)(wr);
            const float4 f1 = *(const float4*)(wr + 8);
            bf16x8 wa;
            wa[0]=(short)f2bf(f0.x); wa[1]=(short)f2bf(f0.y);
            wa[2]=(short)f2bf(f0.z); wa[3]=(short)f2bf(f0.w);
            wa[4]=(short)f2bf(f1.x); wa[5]=(short)f2bf(f1.y);
            wa[6]=(short)f2bf(f1.z); wa[7]=(short)f2bf(f1.w);
            if (rowb==0) ZC0 = MFMA32(wa, pb4.v, ZC0);
            else         ZC1 = MFMA32(wa, pb4.v, ZC1);
        }
    }
    const float gm = gammap[0];
    const int n = n0 + 32*w + l31;
    #pragma unroll
    for (int rowb=0;rowb<2;++rowb){
        #pragma unroll
        for (int reg=0;reg<16;++reg){
            const int c = 32*rowb + (reg&3) + 8*(reg>>2) + 4*g;
            const size_t oi = ((size_t)b*64 + c)*4096 + n;
            const float zv = (rowb==0) ? ZC0[reg] : ZC1[reg];
            out[oi] = gm*(zv + bv[c]) + x[oi];
        }
    }
}

extern "C" void kernel_launch(void* const* d_in, const int* in_sizes, int n_in,
                              void* d_out, int out_size, void* d_ws, size_t ws_size,
                              hipStream_t stream) {
    const float* x  = (const float*)d_in[0];
    const float* y  = (const float*)d_in[1];
    const float* Wq = (const float*)d_in[2];
    const float* bq = (const float*)d_in[3];
    const float* Wk = (const float*)d_in[4];
    // d_in[5] = bk: constant along softmax axis -> mathematically dead
    const float* Wv = (const float*)d_in[6];
    const float* bv = (const float*)d_in[7];
    const float* g  = (const float*)d_in[8];
    float* outp = (float*)d_out;
    unsigned short* wsq = (unsigned short*)d_ws;   // 8*64*4096*2B = 4 MB

    hipLaunchKernelGGL(precompute_q, dim3(256), dim3(256), 0, stream, x, Wq, bq, wsq);
    hipLaunchKernelGGL(fused_attn3, dim3(256), dim3(256), 0, stream,
                       x, y, Wk, wsq, Wv, bv, g, outp);
}